// Round 7
// baseline (12237.041 us; speedup 1.0000x reference)
//
#include <hip/hip_runtime.h>
#include <cstddef>
#include <math.h>

#define SEQ   256
#define BATCH 2048
#define FD    5
#define HD    64
#define NJ    21          // 21 col-groups of 64: j=0..3 main gates, 4..19 aux, 20 attention
#define WAVES 4
#define NTHR  256
#define STEP_STRIDE (BATCH * FD)

// libm activations: accurate to ~1-2 ulp (fast __expf variants amplified to 8e-3 over 256 steps)
__device__ __forceinline__ float sigm(float x) { return 1.0f / (1.0f + expf(-x)); }

__device__ __forceinline__ float wave_sum(float v) {
#pragma unroll
    for (int m = 1; m < 64; m <<= 1) v += __shfl_xor(v, m);
    return v;
}
__device__ __forceinline__ float fma4(float4 w, float4 h, float a) {
    return fmaf(w.x, h.x, fmaf(w.y, h.y, fmaf(w.z, h.z, fmaf(w.w, h.w, a))));
}

// ---- prep: swizzle recurrent weights into UtW[hb][j][lane] (float4 over h=4hb..4hb+3)
//      col = lane + 64*j:  <256 -> U_main[:,col]; <1280 -> U_aux[kk][:,gg]; else W_att row.
//      Wfb[j][lane][8] = {Wf[0..4], bias, 0, 0} (input weights; zeros for attention cols)
__global__ void prep_weights(const float* __restrict__ U_main,
                             const float* __restrict__ U_aux,
                             const float* __restrict__ W_att,
                             const float* __restrict__ W_main,
                             const float* __restrict__ W_aux,
                             const float* __restrict__ b_main,
                             const float* __restrict__ b_aux,
                             float* __restrict__ ws) {
    const int j = blockIdx.x;        // 0..20
    const int lane = threadIdx.x;    // 0..63
    const int col = lane + 64 * j;
    float4* UtW = (float4*)ws;
    float*  Wfb = ws + (size_t)16 * NJ * 64 * 4;
    for (int hb = 0; hb < 16; ++hb) {
        float4 w;
        if (col < 256) {
            w.x = U_main[(4 * hb + 0) * 256 + col];
            w.y = U_main[(4 * hb + 1) * 256 + col];
            w.z = U_main[(4 * hb + 2) * 256 + col];
            w.w = U_main[(4 * hb + 3) * 256 + col];
        } else if (col < 1280) {
            int cp = col - 256, kk = cp >> 7, gg = cp & 127;
            const float* ub = U_aux + (size_t)kk * 64 * 128 + gg;
            w.x = ub[(4 * hb + 0) * 128];
            w.y = ub[(4 * hb + 1) * 128];
            w.z = ub[(4 * hb + 2) * 128];
            w.w = ub[(4 * hb + 3) * 128];
        } else {
            w = *(const float4*)(W_att + (size_t)(col - 1280) * 64 + 4 * hb);
        }
        UtW[((size_t)hb * NJ + j) * 64 + lane] = w;
    }
    float w0 = 0, w1 = 0, w2 = 0, w3 = 0, w4 = 0, bb = 0;
    if (col < 256) {
        w0 = W_main[0 * 256 + col]; w1 = W_main[1 * 256 + col];
        w2 = W_main[2 * 256 + col]; w3 = W_main[3 * 256 + col];
        w4 = W_main[4 * 256 + col]; bb = b_main[col];
    } else if (col < 1280) {
        int cp = col - 256, kk = cp >> 7, gg = cp & 127;
        w0 = W_aux[(kk * 5 + 0) * 128 + gg]; w1 = W_aux[(kk * 5 + 1) * 128 + gg];
        w2 = W_aux[(kk * 5 + 2) * 128 + gg]; w3 = W_aux[(kk * 5 + 3) * 128 + gg];
        w4 = W_aux[(kk * 5 + 4) * 128 + gg]; bb = b_aux[kk * 128 + gg];
    }
    float* d = Wfb + ((size_t)j * 64 + lane) * 8;
    d[0] = w0; d[1] = w1; d[2] = w2; d[3] = w3; d[4] = w4; d[5] = bb; d[6] = 0; d[7] = 0;
}

// P5: in-register MI-LSTM gate/softmax/state update for one row.
// ACC[j] holds column lane+64j: j0=i j1=f j2=o j3=cm, j=2+2k/3+2k aux k=1..8, j20=attn v.
#define P5_ROW(ACC, CREG, RR)                                                 \
    {                                                                         \
        float ii = sigm(ACC[0]), ff = sigm(ACC[1]), oo = sigm(ACC[2]);        \
        float cm = tanhf(ACC[3]);                                             \
        float vv = ACC[20];                                                   \
        float l[9]; l[0] = ii * cm;                                           \
        _Pragma("unroll")                                                     \
        for (int k = 1; k <= 8; ++k)                                          \
            l[k] = sigm(ACC[2 + 2 * k]) * tanhf(ACC[3 + 2 * k]);              \
        float u[9]; float um = -1e30f;                                        \
        _Pragma("unroll")                                                     \
        for (int k = 0; k < 9; ++k) {                                         \
            u[k] = tanhf(wave_sum(l[k] * vv) + batt);                         \
            um = fmaxf(um, u[k]);                                             \
        }                                                                     \
        float den = 0.f, Lh = 0.f;                                            \
        _Pragma("unroll")                                                     \
        for (int k = 0; k < 9; ++k) {                                         \
            float e = expf(u[k] - um); den += e; Lh = fmaf(e, l[k], Lh);      \
        }                                                                     \
        Lh /= den;                                                            \
        float cn = fmaf(ff, CREG, Lh); CREG = cn;                             \
        float hn = oo * tanhf(cn);                                            \
        hbc[wid][RR][lane] = hn; cbc[wid][RR][lane] = cn;                     \
    }

// P7: LSTM2 gates (torch order i,f,g,o) + relu-projection output for one row.
#define P7_ROW(PRE, C2, RR)                                                   \
    {                                                                         \
        float i2 = sigm(PRE[0]), f2 = sigm(PRE[1]);                           \
        float g2 = tanhf(PRE[2]), o2 = sigm(PRE[3]);                          \
        C2 = fmaf(f2, C2, i2 * g2);                                           \
        float hn2 = o2 * tanhf(C2);                                           \
        h2b[wid][RR][lane] = hn2;                                             \
        float e = wave_sum(fmaxf(hn2, 0.f) * linw);                           \
        if (lane == 0) out[(size_t)t * BATCH + row0 + RR] = e + linb;         \
    }

__global__ __launch_bounds__(NTHR, 1)
void minet_wave(const float* __restrict__ Y,
                const float* __restrict__ x1, const float* __restrict__ x2,
                const float* __restrict__ x3, const float* __restrict__ x4,
                const float* __restrict__ x5, const float* __restrict__ x6,
                const float* __restrict__ x7, const float* __restrict__ x8,
                const float4* __restrict__ UtW, const float* __restrict__ Wfb,
                const float* __restrict__ W_ih, const float* __restrict__ W_hh,
                const float* __restrict__ b_ih, const float* __restrict__ b_hh,
                const float* __restrict__ lin_W, const float* __restrict__ lin_b,
                const float* __restrict__ b_att,
                float* __restrict__ out)
{
    // ALL LDS is wave-private (indexed by wid): no __syncthreads anywhere in the time loop.
    __shared__ __align__(16) float hbc[WAVES][2][HD];
    __shared__ __align__(16) float cbc[WAVES][2][HD];
    __shared__ __align__(16) float h2b[WAVES][2][HD];
    __shared__ __align__(16) float inw[WAVES][2][72];   // [row][slot*8+f], slot0=Y,1..8=x

    const int tid  = threadIdx.x;
    const int lane = tid & 63;
    const int wid  = tid >> 6;
    const int row0 = blockIdx.x * (WAVES * 2) + wid * 2;   // this wave's 2 batch rows

    // init wave-private state
    hbc[wid][0][lane] = 0.f; hbc[wid][1][lane] = 0.f;
    cbc[wid][0][lane] = 0.f; cbc[wid][1][lane] = 0.f;
    h2b[wid][0][lane] = 0.f; h2b[wid][1][lane] = 0.f;
    inw[wid][0][lane] = 0.f; inw[wid][1][lane] = 0.f;
    if (lane < 8) { inw[wid][0][64 + lane] = 0.f; inw[wid][1][64 + lane] = 0.f; }

    // LSTM2 weights: lane owns output unit g=lane of each gate q; col = 64q+g, row-contiguous
    float b2q[4];
    const float* wih[4];
    const float* whh[4];
#pragma unroll
    for (int q = 0; q < 4; ++q) {
        b2q[q] = b_ih[64 * q + lane] + b_hh[64 * q + lane];
        wih[q] = W_ih + (size_t)(64 * q + lane) * 64;
        whh[q] = W_hh + (size_t)(64 * q + lane) * 64;
    }
    const float linw = lin_W[lane];
    const float linb = lin_b[0];
    const float batt = b_att[0];

    // input prefetch: 90 values = 2 rows x 9 slots x 5 feats. lane -> idx lane; idx lane+64 if <90
    int rA = lane / 45, remA = lane % 45, sA = remA / 5, fA = remA % 5;
    const float* bA;
    switch (sA) {
        case 0: bA = Y;  break; case 1: bA = x1; break; case 2: bA = x2; break;
        case 3: bA = x3; break; case 4: bA = x4; break; case 5: bA = x5; break;
        case 6: bA = x6; break; case 7: bA = x7; break; default: bA = x8; break;
    }
    const float* psrcA = bA + (size_t)(row0 + rA) * FD + fA;
    const int lofsA = rA * 72 + sA * 8 + fA;

    const bool vB = (lane < 26);
    int idxB = lane + 64;
    int rB = idxB / 45, remB = idxB % 45, sB = remB / 5, fB = remB % 5;
    const float* bB;
    switch (sB) {
        case 0: bB = Y;  break; case 1: bB = x1; break; case 2: bB = x2; break;
        case 3: bB = x3; break; case 4: bB = x4; break; case 5: bB = x5; break;
        case 6: bB = x6; break; case 7: bB = x7; break; default: bB = x8; break;
    }
    const float* psrcB = bB + (size_t)(row0 + rB) * FD + fB;
    const int lofsB = rB * 72 + sB * 8 + fB;

    float pfA = psrcA[0];
    float pfB = vB ? psrcB[0] : 0.f;

    float c1r0 = 0.f, c1r1 = 0.f;   // MI-LSTM cell (unit=lane), rows 0/1
    float c2r0 = 0.f, c2r1 = 0.f;   // LSTM2 cell

    for (int t = 0; t < SEQ; ++t) {
        // publish inputs for step t (wave-private LDS; same-wave RAW -> lgkmcnt only)
        (&inw[wid][0][0])[lofsA] = pfA;
        if (vB) (&inw[wid][0][0])[lofsB] = pfB;
        // prefetch t+1 (hidden under P3)
        if (t + 1 < SEQ) {
            pfA = psrcA[(size_t)(t + 1) * STEP_STRIDE];
            if (vB) pfB = psrcB[(size_t)(t + 1) * STEP_STRIDE];
        }

        // ---- P3: acc[r][j] = bias + in.Wf + h1[r].U[:,col]  (col = lane+64j)
        float acc0[NJ], acc1[NJ];
#pragma unroll
        for (int j = 0; j < NJ; ++j) {
            const float* wb = Wfb + ((size_t)j * 64 + lane) * 8;
            float4 wf = *(const float4*)wb;
            float  w4 = wb[4], bj = wb[5];
            const int s = (j < 4) ? 0 : ((j < 20) ? (1 + ((j - 4) >> 1)) : 0);
            const float* iA = &inw[wid][0][s * 8];
            const float* iB = &inw[wid][1][s * 8];
            float4 a4 = *(const float4*)iA; float a4e = iA[4];
            float4 e4 = *(const float4*)iB; float e4e = iB[4];
            acc0[j] = fmaf(a4e, w4, fma4(wf, a4, bj));
            acc1[j] = fmaf(e4e, w4, fma4(wf, e4, bj));
        }
#pragma unroll 2
        for (int hb = 0; hb < 16; ++hb) {
            float4 hA = *(const float4*)&hbc[wid][0][hb * 4];
            float4 hB = *(const float4*)&hbc[wid][1][hb * 4];
            float4 cA = *(const float4*)&cbc[wid][0][hb * 4];
            float4 cB = *(const float4*)&cbc[wid][1][hb * 4];
            const float4* wrow = UtW + ((size_t)hb * NJ) * 64 + lane;
#pragma unroll
            for (int j = 0; j < 20; ++j) {
                float4 w = wrow[j * 64];
                acc0[j] = fma4(w, hA, acc0[j]);
                acc1[j] = fma4(w, hB, acc1[j]);
            }
            {   // attention column: dot against c_prev
                float4 w = wrow[20 * 64];
                acc0[20] = fma4(w, cA, acc0[20]);
                acc1[20] = fma4(w, cB, acc1[20]);
            }
        }

        // ---- P5: gates + attention softmax + MI state update (in-register, wave-local)
        P5_ROW(acc0, c1r0, 0)
        P5_ROW(acc1, c1r1, 1)

        // ---- P6: LSTM2 pre-activations. pre[q] = b2 + h1(t).Wih[64q+lane] + h2(t-1).Whh[..]
        float pre0[4], pre1[4];
#pragma unroll
        for (int q = 0; q < 4; ++q) { pre0[q] = b2q[q]; pre1[q] = b2q[q]; }
#pragma unroll 4
        for (int hb = 0; hb < 16; ++hb) {
            float4 hA = *(const float4*)&hbc[wid][0][hb * 4];   // h1 just written (same wave)
            float4 hB = *(const float4*)&hbc[wid][1][hb * 4];
            float4 gA = *(const float4*)&h2b[wid][0][hb * 4];   // h2 from t-1
            float4 gB = *(const float4*)&h2b[wid][1][hb * 4];
#pragma unroll
            for (int q = 0; q < 4; ++q) {
                float4 wi = *(const float4*)(wih[q] + hb * 4);
                float4 wh = *(const float4*)(whh[q] + hb * 4);
                pre0[q] = fma4(wh, gA, fma4(wi, hA, pre0[q]));
                pre1[q] = fma4(wh, gB, fma4(wi, hB, pre1[q]));
            }
        }

        // ---- P7: LSTM2 gates + output projection
        P7_ROW(pre0, c2r0, 0)
        P7_ROW(pre1, c2r1, 1)
    }
}

extern "C" void kernel_launch(void* const* d_in, const int* in_sizes, int n_in,
                              void* d_out, int out_size, void* d_ws, size_t ws_size,
                              hipStream_t stream) {
    const float* Y      = (const float*)d_in[0];
    const float* x1     = (const float*)d_in[1];
    const float* x2     = (const float*)d_in[2];
    const float* x3     = (const float*)d_in[3];
    const float* x4     = (const float*)d_in[4];
    const float* x5     = (const float*)d_in[5];
    const float* x6     = (const float*)d_in[6];
    const float* x7     = (const float*)d_in[7];
    const float* x8     = (const float*)d_in[8];
    const float* W_main = (const float*)d_in[9];
    const float* U_main = (const float*)d_in[10];
    const float* b_main = (const float*)d_in[11];
    const float* W_aux  = (const float*)d_in[12];
    const float* U_aux  = (const float*)d_in[13];
    const float* b_aux  = (const float*)d_in[14];
    const float* W_att  = (const float*)d_in[15];
    const float* b_att  = (const float*)d_in[16];
    const float* W_ih   = (const float*)d_in[17];
    const float* W_hh   = (const float*)d_in[18];
    const float* b_ih   = (const float*)d_in[19];
    const float* b_hh   = (const float*)d_in[20];
    const float* lin_W  = (const float*)d_in[21];
    const float* lin_b  = (const float*)d_in[22];
    float* out = (float*)d_out;
    float* ws  = (float*)d_ws;   // UtW 344064 B + Wfb 43008 B = 387 KB

    prep_weights<<<dim3(NJ), dim3(HD), 0, stream>>>(U_main, U_aux, W_att,
                                                    W_main, W_aux, b_main, b_aux, ws);

    const float4* UtW = (const float4*)ws;
    const float*  Wfb = ws + (size_t)16 * NJ * 64 * 4;

    dim3 grid(BATCH / (WAVES * 2));   // 256 blocks, 1/CU; 4 autonomous waves each
    dim3 block(NTHR);
    minet_wave<<<grid, block, 0, stream>>>(Y, x1, x2, x3, x4, x5, x6, x7, x8,
                                           UtW, Wfb, W_ih, W_hh, b_ih, b_hh,
                                           lin_W, lin_b, b_att, out);
}